// Round 6
// baseline (945.998 us; speedup 1.0000x reference)
//
#include <hip/hip_runtime.h>

#define D        64
#define BINROWS  64
#define SUBCAP   256        // slots per (shard,bin): mean ~161, sigma ~12.7 -> +7.4 sigma
#define NSHARD   8
#define NBINS_MAX 1568      // 224*7 (scan layout); n=100k -> 1563 bins used
#define CHUNK    3072       // 49.4 KB LDS -> 3 blocks/CU in expand
#define PER_TH   (CHUNK / 256)   // 12
#define FSTRIDE  68         // fp32 facc row stride (272 B, 16B-aligned)
#define CURSTRIDE 16        // ints per cursor -> own 64 B line
#define FTH      512        // fused block size

typedef __attribute__((ext_vector_type(8))) short short8;
typedef __attribute__((ext_vector_type(4))) float floatx4;

__device__ __forceinline__ unsigned short f2bf(float f) {
    unsigned u = __float_as_uint(f);
    u += 0x7fffu + ((u >> 16) & 1u);   // RNE
    return (unsigned short)(u >> 16);
}
__device__ __forceinline__ float bf2f(unsigned short u) {
    return __uint_as_float(((unsigned)u) << 16);
}

// ---------------------------------------------------------------------------
// Expand v5 (unchanged): register payloads + 1568-bin LDS counting sort +
// sorted run-coalesced write-out; convert + wfrag pack folded in.
// payload.x = (m<<23)|(rowInBin<<17)|col   payload.y = val bits
// ---------------------------------------------------------------------------
__global__ __launch_bounds__(256) void expand_bin_kernel(
    const int* __restrict__ LI_rows, const int* __restrict__ LI_cols, const float* __restrict__ LI_vals,
    const int* __restrict__ L_rows,  const int* __restrict__ L_cols,  const float* __restrict__ L_vals,
    int* __restrict__ cursorP, uint2* __restrict__ seg, int E, int nbins,
    const float* __restrict__ ebs, unsigned short* __restrict__ ebs16, int total4,
    const float* __restrict__ W_side, const float* __restrict__ W_dot,
    unsigned short* __restrict__ Wfrag)
{
    __shared__ uint2 sorted[CHUNK];               // 24 KB
    __shared__ unsigned short sbin[CHUNK];        // 6 KB
    __shared__ int hist[NBINS_MAX];               // 6.125 KB
    __shared__ int cur[NBINS_MAX];
    __shared__ int gbase[NBINS_MAX];
    __shared__ int tsum[256];

    int t  = threadIdx.x;

    // ---- folded-in convert: ebs fp32 -> bf16 (grid-stride) ----
    for (int i = blockIdx.x * 256 + t; i < total4; i += gridDim.x * 256) {
        float4 v = ((const float4*)ebs)[i];
        ushort4 o;
        o.x = f2bf(v.x); o.y = f2bf(v.y); o.z = f2bf(v.z); o.w = f2bf(v.w);
        ((ushort4*)ebs16)[i] = o;
    }
    // ---- folded-in wfrag pack (blocks 0..3 = 1024 threads = 16 frags) ----
    if (blockIdx.x < 4) {
        int tt = blockIdx.x * 256 + t;
        int f = tt >> 6;
        int l = tt & 63;
        int jt = f >> 2, kt = f & 3;
        int q = l >> 4, nl = l & 15;
        int nn = jt * 16 + nl;
#pragma unroll
        for (int j = 0; j < 8; ++j) {
            int k = kt * 32 + q * 8 + j;
            float w = (k < 64) ? W_side[k * 64 + nn] : W_dot[(k - 64) * 64 + nn];
            Wfrag[(size_t)f * 512 + l * 8 + j] = f2bf(w);
        }
    }

    int c0 = blockIdx.x * CHUNK;
    int sh = blockIdx.x & (NSHARD - 1);
    int twoE = 2 * E;
    int chunkcnt = twoE - c0; if (chunkcnt > CHUNK) chunkcnt = CHUNK;

    for (int b = t; b < NBINS_MAX; b += 256) hist[b] = 0;
    __syncthreads();

    unsigned rm[PER_TH];
    uint2    cv[PER_TH];

    // Phase A: read edges into registers, histogram bins
#pragma unroll
    for (int k = 0; k < PER_TH; ++k) {
        int e = c0 + k * 256 + t;
        rm[k] = 0xFFFFFFFFu;
        if (e < twoE) {
            int m = (e >= E) ? 1 : 0;
            int r, cl; float v;
            if (m) { r = L_rows[e - E]; cl = L_cols[e - E]; v = L_vals[e - E]; }
            else   { r = LI_rows[e];    cl = LI_cols[e];    v = LI_vals[e]; }
            rm[k] = (unsigned)r | ((unsigned)m << 17);
            cv[k] = make_uint2((unsigned)cl, __float_as_uint(v));
            atomicAdd(&hist[r >> 6], 1);
        }
    }
    __syncthreads();

    // Phase B: exclusive scan of hist (224 threads x 7 keys + block scan)
    int loc[7]; int tot = 0;
    if (t < 224) {
#pragma unroll
        for (int i = 0; i < 7; ++i) { loc[i] = tot; tot += hist[t * 7 + i]; }
    }
    tsum[t] = (t < 224) ? tot : 0;
    __syncthreads();
    for (int step = 1; step < 256; step <<= 1) {
        int add = (t >= step) ? tsum[t - step] : 0;
        __syncthreads();
        tsum[t] += add;
        __syncthreads();
    }
    int tbase = tsum[t] - ((t < 224) ? tot : 0);
    if (t < 224) {
#pragma unroll
        for (int i = 0; i < 7; ++i) {
            int key = t * 7 + i;
            cur[key] = tbase + loc[i];
        }
    }
    __syncthreads();

    // Phase B2: reserve global runs in this WG's shard (padded cursors)
    for (int b = t; b < nbins; b += 256) {
        int c = hist[b];
        gbase[b] = c ? atomicAdd(&cursorP[(sh * NBINS_MAX + b) * CURSTRIDE], c) : 0;
    }

    // Phase C: scatter payloads into the LDS-sorted array
#pragma unroll
    for (int k = 0; k < PER_TH; ++k) {
        unsigned g = rm[k];
        if (g == 0xFFFFFFFFu) continue;
        int r   = (int)(g & 0x1FFFFu);
        int m   = (int)((g >> 17) & 1u);
        int bin = r >> 6;
        int rank = atomicAdd(&cur[bin], 1);
        sorted[rank] = make_uint2(((unsigned)m << 23) | ((unsigned)(r & 63) << 17) | cv[k].x, cv[k].y);
        sbin[rank]   = (unsigned short)bin;
    }
    __syncthreads();

    // Phase D: coalesced run write-out; offs derived as cur-hist
    for (int i = t; i < chunkcnt; i += 256) {
        int bin = sbin[i];
        int off = cur[bin] - hist[bin];
        int pos = gbase[bin] + (i - off);
        if (pos < SUBCAP)
            seg[((size_t)(sh * NBINS_MAX) + bin) * SUBCAP + pos] = sorted[i];
    }
}

// ---------------------------------------------------------------------------
// Fused v11: entry-parallel gather + LDS fp32 atomic accumulation.
//  - No counting sort: rank = shardPrefix + pos is deterministic -> hist/
//    scan/scatter prologue (14 barriers) deleted.
//  - 32 groups x 16 lanes process entries at uniform stride 32: perfectly
//    balanced (R5 analysis: old per-group maxlen imbalance cost 1.5-2x),
//    4 independent entries per trip (straight-line unroll, no dep chain).
//  - ds_add_f32 accumulate into fp32 facc with per-group column rotation
//    p=g&3: instr jj adds col 4l+((jj+p)&3) -> the 4 groups of a wave hit
//    the 4 distinct mod-4 bank classes -> exactly 2-way (free) instead of
//    8-way. Value rotation = 64-bit ror by 16p (shift counts loop-invariant).
//  - Epilogue = R0's verified fp32 MFMA epilogue (t<256).
// ---------------------------------------------------------------------------
__global__ __launch_bounds__(FTH) void fused_kernel(
    const uint2* __restrict__ seg, const int* __restrict__ cursorP,
    const unsigned short* __restrict__ ebs16,
    const float* __restrict__ entity,
    const unsigned short* __restrict__ Wfrag,
    float* __restrict__ out, int n)
{
    __shared__ __align__(16) float facc[2 * BINROWS * FSTRIDE];  // 34816 B
    __shared__ __align__(16) uint2 sseg[NSHARD * SUBCAP];        // 16384 B

    int t = threadIdx.x;
    int b = blockIdx.x;

    // zero facc (8704 floats = 2176 float4)
#pragma unroll
    for (int i = t; i < 2 * BINROWS * FSTRIDE / 4; i += FTH)
        ((float4*)facc)[i] = make_float4(0.f, 0.f, 0.f, 0.f);

    // cursors + in-register prefix over shards
    int clen[NSHARD], pref[NSHARD]; int total = 0;
#pragma unroll
    for (int sh = 0; sh < NSHARD; ++sh) {
        int c = cursorP[(sh * NBINS_MAX + b) * CURSTRIDE];
        clen[sh] = c < SUBCAP ? c : SUBCAP;
        pref[sh] = total; total += clen[sh];
    }

    // compact load: deterministic rank, no atomics, no sort
#pragma unroll
    for (int k = 0; k < 4; ++k) {
        int i = k * FTH + t;          // 0..2047
        int sh = i >> 8; int pos = i & 255;
        if (pos < clen[sh])
            sseg[pref[sh] + pos] = seg[((size_t)(sh * NBINS_MAX) + b) * SUBCAP + pos];
    }
    __syncthreads();

    // ---- balanced entry-parallel gather ----
    int g  = t >> 4;                  // group 0..31
    int l  = t & 15;
    int p  = g & 3;                   // per-group bank-class rotation
    unsigned s1 = 16u * (unsigned)p;  // ror amount (bits)
    unsigned s2 = (64u - s1) & 63u;
    int off0 = 4 * l + ((0 + p) & 3);
    int off1 = 4 * l + ((1 + p) & 3);
    int off2 = 4 * l + ((2 + p) & 3);
    int off3 = 4 * l + ((3 + p) & 3);

    int smax = (total + 31) >> 5;     // entries per group (uniform)
    for (int s = 0; s < smax; s += 4) {
        float vv[4]; unsigned key[4]; unsigned long long x64[4];
#pragma unroll
        for (int u = 0; u < 4; ++u) {
            int e  = (s + u) * 32 + g;
            bool ok = e < total;
            int ec = ok ? e : (total - 1);     // total>=1 whenever smax>0
            uint2 en = sseg[ec];               // 16-lane broadcast
            vv[u]  = ok ? __uint_as_float(en.y) : 0.f;
            key[u] = (en.x >> 17) & 127u;
            unsigned row = en.x & 0x1FFFFu;    // valid row (clamped entry)
            x64[u] = *(const unsigned long long*)(ebs16 + (row << 6) + (l << 2));
        }
#pragma unroll
        for (int u = 0; u < 4; ++u) {
            unsigned long long r64 = (x64[u] >> s1) | (x64[u] << s2);  // ror by 16p
            unsigned rlo = (unsigned)r64;
            unsigned rhi = (unsigned)(r64 >> 32);
            float v0 = __uint_as_float(rlo << 16);
            float v1 = __uint_as_float(rlo & 0xFFFF0000u);
            float v2 = __uint_as_float(rhi << 16);
            float v3 = __uint_as_float(rhi & 0xFFFF0000u);
            float* rp = facc + key[u] * FSTRIDE;
            float w = vv[u];
            atomicAdd(rp + off0, w * v0);
            atomicAdd(rp + off1, w * v1);
            atomicAdd(rp + off2, w * v2);
            atomicAdd(rp + off3, w * v3);
        }
    }
    __syncthreads();

    // --- MFMA epilogue (R0-verified, fp32 facc) on waves 0..3 ---
    if (t < 256) {
        int w = t >> 6;
        int l6 = t & 63;
        int q = l6 >> 4, mcol = l6 & 15;
        int rowbase = b * BINROWS + w * 16;
        int growA = rowbase + mcol;
        int binrow = w * 16 + mcol;
        const float* faccLI = facc;
        const float* faccL  = facc + BINROWS * FSTRIDE;

        floatx4 accv[4];
#pragma unroll
        for (int jt = 0; jt < 4; ++jt) accv[jt] = (floatx4){0.f, 0.f, 0.f, 0.f};

#pragma unroll
        for (int kt = 0; kt < 4; ++kt) {
            short8 af;
            if (kt < 2) {
                const float4* ap = (const float4*)(faccLI + binrow * FSTRIDE + kt * 32 + q * 8);
                float4 a0 = ap[0], a1 = ap[1];
                af[0] = (short)f2bf(a0.x); af[1] = (short)f2bf(a0.y);
                af[2] = (short)f2bf(a0.z); af[3] = (short)f2bf(a0.w);
                af[4] = (short)f2bf(a1.x); af[5] = (short)f2bf(a1.y);
                af[6] = (short)f2bf(a1.z); af[7] = (short)f2bf(a1.w);
            } else {
                const float4* lp = (const float4*)(faccL + binrow * FSTRIDE + (kt - 2) * 32 + q * 8);
                float4 l0 = lp[0], l1 = lp[1];
                float4 e0 = make_float4(0.f, 0.f, 0.f, 0.f), e1 = e0;
                if (growA < n) {
                    const float4* ep = (const float4*)(entity + (size_t)growA * D + (kt - 2) * 32 + q * 8);
                    e0 = ep[0]; e1 = ep[1];
                }
                af[0] = (short)f2bf(l0.x * e0.x); af[1] = (short)f2bf(l0.y * e0.y);
                af[2] = (short)f2bf(l0.z * e0.z); af[3] = (short)f2bf(l0.w * e0.w);
                af[4] = (short)f2bf(l1.x * e1.x); af[5] = (short)f2bf(l1.y * e1.y);
                af[6] = (short)f2bf(l1.z * e1.z); af[7] = (short)f2bf(l1.w * e1.w);
            }
#pragma unroll
            for (int jt = 0; jt < 4; ++jt) {
                const short8 bf = *(const short8*)(Wfrag + (size_t)(jt * 4 + kt) * 512 + (size_t)l6 * 8);
                accv[jt] = __builtin_amdgcn_mfma_f32_16x16x32_bf16(af, bf, accv[jt], 0, 0, 0);
            }
        }

#pragma unroll
        for (int jt = 0; jt < 4; ++jt) {
#pragma unroll
            for (int r = 0; r < 4; ++r) {
                int grow = rowbase + q * 4 + r;
                if (grow < n) {
                    float v = accv[jt][r];
                    v = v > 0.f ? v : 0.2f * v;
                    out[(size_t)grow * D + jt * 16 + mcol] = v;
                }
            }
        }
    }
}

// ---------------------------------------------------------------------------
// Fallback path (workspace too small): R1 atomic scatter + fp32 epilogue.
// ---------------------------------------------------------------------------
__global__ void scatter_kernel(
    const float* __restrict__ LI_vals, const int* __restrict__ LI_rows, const int* __restrict__ LI_cols,
    const float* __restrict__ L_vals,  const int* __restrict__ L_rows,  const int* __restrict__ L_cols,
    const float* __restrict__ ebs,
    float* __restrict__ accLI, float* __restrict__ accL, int E)
{
    long long t = (long long)blockIdx.x * blockDim.x + threadIdx.x;
    long long e2 = t >> 4;
    if (e2 >= 2LL * E) return;
    int c = ((int)t & 15) << 2;
    const float* vals; const int* rows; const int* cols; float* acc; int e;
    if (e2 < E) { vals = LI_vals; rows = LI_rows; cols = LI_cols; acc = accLI; e = (int)e2; }
    else        { vals = L_vals;  rows = L_rows;  cols = L_cols;  acc = accL;  e = (int)(e2 - E); }
    float v = vals[e]; int r = rows[e]; int cl = cols[e];
    const float4 x = *(const float4*)(ebs + (size_t)cl * D + c);
    float* o = acc + (size_t)r * D + c;
    unsafeAtomicAdd(o + 0, v * x.x);
    unsafeAtomicAdd(o + 1, v * x.y);
    unsafeAtomicAdd(o + 2, v * x.z);
    unsafeAtomicAdd(o + 3, v * x.w);
}

__global__ __launch_bounds__(256) void epilogue_kernel(
    const float* __restrict__ acc, const float* __restrict__ entity,
    const float* __restrict__ W_side, const float* __restrict__ W_dot,
    float* __restrict__ out, int n)
{
    int lane = threadIdx.x & 63;
    int wave = (blockIdx.x << 2) | (threadIdx.x >> 6);
    int row  = (wave << 6) + lane;
    bool valid = row < n;
    const float* accLI = acc;
    const float* accL  = acc + (size_t)n * D;
    float a[D], b[D];
    if (valid) {
        const float4* ap = (const float4*)(accLI  + (size_t)row * D);
        const float4* lp = (const float4*)(accL   + (size_t)row * D);
        const float4* ep = (const float4*)(entity + (size_t)row * D);
#pragma unroll
        for (int qq = 0; qq < 16; ++qq) {
            float4 av = ap[qq]; float4 lv = lp[qq]; float4 ev = ep[qq];
            a[4*qq+0] = av.x; a[4*qq+1] = av.y; a[4*qq+2] = av.z; a[4*qq+3] = av.w;
            b[4*qq+0] = lv.x * ev.x; b[4*qq+1] = lv.y * ev.y;
            b[4*qq+2] = lv.z * ev.z; b[4*qq+3] = lv.w * ev.w;
        }
    } else {
#pragma unroll
        for (int qq = 0; qq < D; ++qq) { a[qq] = 0.f; b[qq] = 0.f; }
    }
    float4* op = (float4*)(out + (size_t)row * D);
#pragma unroll 1
    for (int jc = 0; jc < 16; ++jc) {
        float a0 = 0.f, a1 = 0.f, a2 = 0.f, a3 = 0.f;
#pragma unroll
        for (int k = 0; k < D; ++k) {
            float4 w1 = *(const float4*)(W_side + (k << 6) + (jc << 2));
            float4 w2 = *(const float4*)(W_dot  + (k << 6) + (jc << 2));
            a0 += a[k] * w1.x + b[k] * w2.x;
            a1 += a[k] * w1.y + b[k] * w2.y;
            a2 += a[k] * w1.z + b[k] * w2.z;
            a3 += a[k] * w1.w + b[k] * w2.w;
        }
        float4 r;
        r.x = a0 > 0.f ? a0 : 0.2f * a0;
        r.y = a1 > 0.f ? a1 : 0.2f * a1;
        r.z = a2 > 0.f ? a2 : 0.2f * a2;
        r.w = a3 > 0.f ? a3 : 0.2f * a3;
        if (valid) op[jc] = r;
    }
}

extern "C" void kernel_launch(void* const* d_in, const int* in_sizes, int n_in,
                              void* d_out, int out_size, void* d_ws, size_t ws_size,
                              hipStream_t stream) {
    const float* ebs     = (const float*)d_in[0];
    const float* entity  = (const float*)d_in[1];
    const float* W_side  = (const float*)d_in[2];
    const float* W_dot   = (const float*)d_in[3];
    const float* LI_vals = (const float*)d_in[4];
    const float* L_vals  = (const float*)d_in[5];
    const int*   LI_rows = (const int*)d_in[6];
    const int*   LI_cols = (const int*)d_in[7];
    const int*   L_rows  = (const int*)d_in[8];
    const int*   L_cols  = (const int*)d_in[9];
    float* out = (float*)d_out;

    int E = in_sizes[4];
    int n = in_sizes[0] / D;
    int nbins = (n + BINROWS - 1) / BINROWS;

    size_t curBytes = (size_t)NSHARD * NBINS_MAX * CURSTRIDE * sizeof(int);   // 0.80 MB
    size_t segBytes = (size_t)NSHARD * NBINS_MAX * SUBCAP * sizeof(uint2);    // 25.7 MB
    size_t ebsBytes = (size_t)n * D * sizeof(unsigned short);                 // 12.8 MB
    size_t wfBytes  = (size_t)16 * 512 * sizeof(unsigned short);              // 16 KB
    size_t need = curBytes + segBytes + ebsBytes + wfBytes;

    if (ws_size >= need && nbins <= NBINS_MAX && n <= 131072) {
        int*            cursorP = (int*)d_ws;
        uint2*          seg     = (uint2*)((char*)d_ws + curBytes);
        unsigned short* ebs16   = (unsigned short*)((char*)d_ws + curBytes + segBytes);
        unsigned short* Wfrag   = (unsigned short*)((char*)d_ws + curBytes + segBytes + ebsBytes);

        hipMemsetAsync(cursorP, 0, curBytes, stream);

        int total4 = n * D / 4;
        int xblocks = (2 * E + CHUNK - 1) / CHUNK;
        expand_bin_kernel<<<xblocks, 256, 0, stream>>>(
            LI_rows, LI_cols, LI_vals, L_rows, L_cols, L_vals,
            cursorP, seg, E, nbins,
            ebs, ebs16, total4, W_side, W_dot, Wfrag);

        fused_kernel<<<nbins, FTH, 0, stream>>>(
            seg, cursorP, ebs16, entity, Wfrag, out, n);
    } else {
        size_t accBytes = (size_t)2 * n * D * sizeof(float);
        float* acc   = (float*)d_ws;
        float* accLI = acc;
        float* accL  = accLI + (size_t)n * D;
        hipMemsetAsync(d_ws, 0, accBytes, stream);
        long long totalThreads = 2LL * E * 16;
        int sblocks = (int)((totalThreads + 255) / 256);
        scatter_kernel<<<sblocks, 256, 0, stream>>>(
            LI_vals, LI_rows, LI_cols, L_vals, L_rows, L_cols, ebs, accLI, accL, E);
        int nTiles = (n + 63) / 64;
        epilogue_kernel<<<(nTiles + 3) / 4, 256, 0, stream>>>(
            acc, entity, W_side, W_dot, out, n);
    }
}

// Round 7
// 222.280 us; speedup vs baseline: 4.2559x; 4.2559x over previous
//
#include <hip/hip_runtime.h>

#define D        64
#define BINROWS  64
#define SUBCAP   256        // slots per (shard,bin): mean ~161, sigma ~12.7 -> +7.4 sigma
#define NSHARD   8
#define NBINS_MAX 1568      // 224*7 (scan layout); n=100k -> 1563 bins used
#define CHUNK    3072       // 49.4 KB LDS -> 3 blocks/CU in expand
#define PER_TH   (CHUNK / 256)   // 12
#define FS16     72         // bf16 facc row stride: 144 B rows, 16B-aligned, 2-way banks (free)
#define CURSTRIDE 16        // ints per cursor -> own 64 B line
#define FTH      512        // fused block size: 4 keys/group

typedef __attribute__((ext_vector_type(8))) short short8;
typedef __attribute__((ext_vector_type(4))) float floatx4;

__device__ __forceinline__ unsigned short f2bf(float f) {
    unsigned u = __float_as_uint(f);
    u += 0x7fffu + ((u >> 16) & 1u);   // RNE
    return (unsigned short)(u >> 16);
}
__device__ __forceinline__ float bf2f(unsigned short u) {
    return __uint_as_float(((unsigned)u) << 16);
}

// ---------------------------------------------------------------------------
// Expand v5 (unchanged): register payloads + 1568-bin LDS counting sort +
// sorted run-coalesced write-out; convert + wfrag pack folded in.
// payload.x = (m<<23)|(rowInBin<<17)|col   payload.y = val bits
// ---------------------------------------------------------------------------
__global__ __launch_bounds__(256) void expand_bin_kernel(
    const int* __restrict__ LI_rows, const int* __restrict__ LI_cols, const float* __restrict__ LI_vals,
    const int* __restrict__ L_rows,  const int* __restrict__ L_cols,  const float* __restrict__ L_vals,
    int* __restrict__ cursorP, uint2* __restrict__ seg, int E, int nbins,
    const float* __restrict__ ebs, unsigned short* __restrict__ ebs16, int total4,
    const float* __restrict__ W_side, const float* __restrict__ W_dot,
    unsigned short* __restrict__ Wfrag)
{
    __shared__ uint2 sorted[CHUNK];               // 24 KB
    __shared__ unsigned short sbin[CHUNK];        // 6 KB
    __shared__ int hist[NBINS_MAX];               // 6.125 KB
    __shared__ int cur[NBINS_MAX];
    __shared__ int gbase[NBINS_MAX];
    __shared__ int tsum[256];

    int t  = threadIdx.x;

    // ---- folded-in convert: ebs fp32 -> bf16 (grid-stride) ----
    for (int i = blockIdx.x * 256 + t; i < total4; i += gridDim.x * 256) {
        float4 v = ((const float4*)ebs)[i];
        ushort4 o;
        o.x = f2bf(v.x); o.y = f2bf(v.y); o.z = f2bf(v.z); o.w = f2bf(v.w);
        ((ushort4*)ebs16)[i] = o;
    }
    // ---- folded-in wfrag pack (blocks 0..3 = 1024 threads = 16 frags) ----
    if (blockIdx.x < 4) {
        int tt = blockIdx.x * 256 + t;
        int f = tt >> 6;
        int l = tt & 63;
        int jt = f >> 2, kt = f & 3;
        int q = l >> 4, nl = l & 15;
        int nn = jt * 16 + nl;
#pragma unroll
        for (int j = 0; j < 8; ++j) {
            int k = kt * 32 + q * 8 + j;
            float w = (k < 64) ? W_side[k * 64 + nn] : W_dot[(k - 64) * 64 + nn];
            Wfrag[(size_t)f * 512 + l * 8 + j] = f2bf(w);
        }
    }

    int c0 = blockIdx.x * CHUNK;
    int sh = blockIdx.x & (NSHARD - 1);
    int twoE = 2 * E;
    int chunkcnt = twoE - c0; if (chunkcnt > CHUNK) chunkcnt = CHUNK;

    for (int b = t; b < NBINS_MAX; b += 256) hist[b] = 0;
    __syncthreads();

    unsigned rm[PER_TH];
    uint2    cv[PER_TH];

    // Phase A: read edges into registers, histogram bins
#pragma unroll
    for (int k = 0; k < PER_TH; ++k) {
        int e = c0 + k * 256 + t;
        rm[k] = 0xFFFFFFFFu;
        if (e < twoE) {
            int m = (e >= E) ? 1 : 0;
            int r, cl; float v;
            if (m) { r = L_rows[e - E]; cl = L_cols[e - E]; v = L_vals[e - E]; }
            else   { r = LI_rows[e];    cl = LI_cols[e];    v = LI_vals[e]; }
            rm[k] = (unsigned)r | ((unsigned)m << 17);
            cv[k] = make_uint2((unsigned)cl, __float_as_uint(v));
            atomicAdd(&hist[r >> 6], 1);
        }
    }
    __syncthreads();

    // Phase B: exclusive scan of hist (224 threads x 7 keys + block scan)
    int loc[7]; int tot = 0;
    if (t < 224) {
#pragma unroll
        for (int i = 0; i < 7; ++i) { loc[i] = tot; tot += hist[t * 7 + i]; }
    }
    tsum[t] = (t < 224) ? tot : 0;
    __syncthreads();
    for (int step = 1; step < 256; step <<= 1) {
        int add = (t >= step) ? tsum[t - step] : 0;
        __syncthreads();
        tsum[t] += add;
        __syncthreads();
    }
    int tbase = tsum[t] - ((t < 224) ? tot : 0);
    if (t < 224) {
#pragma unroll
        for (int i = 0; i < 7; ++i) {
            int key = t * 7 + i;
            cur[key] = tbase + loc[i];
        }
    }
    __syncthreads();

    // Phase B2: reserve global runs in this WG's shard (padded cursors)
    for (int b = t; b < nbins; b += 256) {
        int c = hist[b];
        gbase[b] = c ? atomicAdd(&cursorP[(sh * NBINS_MAX + b) * CURSTRIDE], c) : 0;
    }

    // Phase C: scatter payloads into the LDS-sorted array
#pragma unroll
    for (int k = 0; k < PER_TH; ++k) {
        unsigned g = rm[k];
        if (g == 0xFFFFFFFFu) continue;
        int r   = (int)(g & 0x1FFFFu);
        int m   = (int)((g >> 17) & 1u);
        int bin = r >> 6;
        int rank = atomicAdd(&cur[bin], 1);
        sorted[rank] = make_uint2(((unsigned)m << 23) | ((unsigned)(r & 63) << 17) | cv[k].x, cv[k].y);
        sbin[rank]   = (unsigned short)bin;
    }
    __syncthreads();

    // Phase D: coalesced run write-out; offs derived as cur-hist
    for (int i = t; i < chunkcnt; i += 256) {
        int bin = sbin[i];
        int off = cur[bin] - hist[bin];
        int pos = gbase[bin] + (i - off);
        if (pos < SUBCAP)
            seg[((size_t)(sh * NBINS_MAX) + bin) * SUBCAP + pos] = sorted[i];
    }
}

// ---------------------------------------------------------------------------
// Fused v12: R5's v10b structure (512 thr, 32 groups x 16 lanes x 4 keys,
// bf16 facc, 69.2 us measured) with the gather trip REGION-FENCED via
// sched_barrier(0): [8 ds_read] | fence | [8 global gathers] | fence |
// [8 consumes]. R5 evidence (time ratio v8/v10b = maxlen ratio, VGPR=36)
// showed the scheduler sank loads-B below consume-A, serializing the two
// batches -> only ~4 loads in flight. The fences force 8 in flight and a
// counted vmcnt at first consume: round-trips per trip 2 -> 1.
// ---------------------------------------------------------------------------
__global__ __launch_bounds__(FTH) void fused_kernel(
    const uint2* __restrict__ seg, const int* __restrict__ cursorP,
    const unsigned short* __restrict__ ebs16,
    const float* __restrict__ entity,
    const unsigned short* __restrict__ Wfrag,
    float* __restrict__ out, int n)
{
    __shared__ __align__(16) char shmem[2 * BINROWS * FS16 * 2];  // 18432 B
    __shared__ int hist[128];
    __shared__ int offs[128];
    __shared__ int cur[128];
    uint2* sseg = (uint2*)shmem;                 // sorted entries (<=2048*8 B = 16 KB)
    unsigned short* facc = (unsigned short*)shmem;  // bf16 acc, reused after barrier

    int t = threadIdx.x;
    int b = blockIdx.x;

    if (t < 128) hist[t] = 0;
    __syncthreads();

    // Cooperative shard load: 2048 slots over 512 threads -> 4 slots each
    int clen[NSHARD];
#pragma unroll
    for (int sh = 0; sh < NSHARD; ++sh) {
        int c = cursorP[(sh * NBINS_MAX + b) * CURSTRIDE];
        clen[sh] = c < SUBCAP ? c : SUBCAP;
    }
    uint2 held[4];
    unsigned hmask = 0;
#pragma unroll
    for (int k = 0; k < 4; ++k) {
        int i   = k * FTH + t;       // 0..2047
        int sh  = i >> 8;
        int pos = i & 255;
        if (pos < clen[sh]) {
            held[k] = seg[((size_t)(sh * NBINS_MAX) + b) * SUBCAP + pos];
            hmask |= (1u << k);
            atomicAdd(&hist[(held[k].x >> 17) & 127u], 1);
        }
    }
    __syncthreads();

    // exclusive scan over 128 keys
    if (t < 128) offs[t] = hist[t];
    __syncthreads();
    for (int step = 1; step < 128; step <<= 1) {
        int add = 0;
        if (t < 128 && t >= step) add = offs[t - step];
        __syncthreads();
        if (t < 128) offs[t] += add;
        __syncthreads();
    }
    if (t < 128) {
        int excl = offs[t] - hist[t];
        offs[t] = excl;
        cur[t]  = excl;
    }
    __syncthreads();

#pragma unroll
    for (int k = 0; k < 4; ++k) {
        if (hmask & (1u << k)) {
            unsigned key = (held[k].x >> 17) & 127u;
            int rank = atomicAdd(&cur[key], 1);
            sseg[rank] = held[k];
        }
    }
    __syncthreads();

    // Gather: group g (16 lanes) owns keys [g*4, g*4+4); region-fenced
    // unroll-2 (8 loads in flight per trip).
    int g  = t >> 4;                 // 0..31
    int l4 = (t & 15) << 2;
    int beg[4], len[4], lenm1[4];
    int maxlen = 0;
#pragma unroll
    for (int kk = 0; kk < 4; ++kk) {
        int key = g * 4 + kk;
        beg[kk]   = offs[key];
        len[kk]   = hist[key];
        lenm1[kk] = len[kk] > 0 ? len[kk] - 1 : 0;
        maxlen = max(maxlen, len[kk]);
    }
    floatx4 a4[4];
#pragma unroll
    for (int kk = 0; kk < 4; ++kk) a4[kk] = (floatx4){0.f, 0.f, 0.f, 0.f};

    for (int s = 0; s < maxlen; s += 2) {
        // region 1: all 8 sseg LDS reads
        uint2 enA[4], enB[4];
#pragma unroll
        for (int kk = 0; kk < 4; ++kk) {
            enA[kk] = sseg[beg[kk] + min(s,     lenm1[kk])];
            enB[kk] = sseg[beg[kk] + min(s + 1, lenm1[kk])];
        }
        __builtin_amdgcn_sched_barrier(0);
        // region 2: all 8 global gathers (stay in flight together)
        ushort4 xA[4], xB[4];
#pragma unroll
        for (int kk = 0; kk < 4; ++kk) {
            unsigned ea = (s < len[kk]) ? (enA[kk].x & 0x1FFFFu) : 0u;
            xA[kk] = *(const ushort4*)(ebs16 + (ea << 6) + l4);
        }
#pragma unroll
        for (int kk = 0; kk < 4; ++kk) {
            unsigned eb = (s + 1 < len[kk]) ? (enB[kk].x & 0x1FFFFu) : 0u;
            xB[kk] = *(const ushort4*)(ebs16 + (eb << 6) + l4);
        }
        __builtin_amdgcn_sched_barrier(0);
        // region 3: consumes (first use triggers a counted vmcnt)
#pragma unroll
        for (int kk = 0; kk < 4; ++kk) {
            float vv = (s < len[kk]) ? __uint_as_float(enA[kk].y) : 0.f;
            ushort4 x = xA[kk];
            a4[kk][0] += vv * bf2f(x.x);
            a4[kk][1] += vv * bf2f(x.y);
            a4[kk][2] += vv * bf2f(x.z);
            a4[kk][3] += vv * bf2f(x.w);
        }
#pragma unroll
        for (int kk = 0; kk < 4; ++kk) {
            float vv = (s + 1 < len[kk]) ? __uint_as_float(enB[kk].y) : 0.f;
            ushort4 x = xB[kk];
            a4[kk][0] += vv * bf2f(x.x);
            a4[kk][1] += vv * bf2f(x.y);
            a4[kk][2] += vv * bf2f(x.z);
            a4[kk][3] += vv * bf2f(x.w);
        }
    }
    __syncthreads();   // all sseg reads done before facc overwrites the union

#pragma unroll
    for (int kk = 0; kk < 4; ++kk) {
        int key = g * 4 + kk;
        ushort4 o;
        o.x = f2bf(a4[kk][0]); o.y = f2bf(a4[kk][1]);
        o.z = f2bf(a4[kk][2]); o.w = f2bf(a4[kk][3]);
        *(ushort4*)(facc + ((size_t)(key >> 6) * BINROWS + (key & 63)) * FS16 + l4) = o;
    }
    __syncthreads();

    // --- MFMA epilogue on waves 0..3 (t<256): wave w owns bin-rows [w*16,+16) ---
    if (t < 256) {
        int w = t >> 6;
        int l = t & 63;
        int q = l >> 4, mcol = l & 15;
        int rowbase = b * BINROWS + w * 16;
        int growA = rowbase + mcol;
        int binrow = w * 16 + mcol;
        const unsigned short* faccLI = facc;
        const unsigned short* faccL  = facc + BINROWS * FS16;

        floatx4 accv[4];
#pragma unroll
        for (int jt = 0; jt < 4; ++jt) accv[jt] = (floatx4){0.f, 0.f, 0.f, 0.f};

#pragma unroll
        for (int kt = 0; kt < 4; ++kt) {
            short8 af;
            if (kt < 2) {
                // bf16 fragment already in stored format: one ds_read_b128
                af = *(const short8*)(faccLI + (size_t)binrow * FS16 + kt * 32 + q * 8);
            } else {
                short8 lv = *(const short8*)(faccL + (size_t)binrow * FS16 + (kt - 2) * 32 + q * 8);
                float4 e0 = make_float4(0.f, 0.f, 0.f, 0.f), e1 = e0;
                if (growA < n) {
                    const float4* ep = (const float4*)(entity + (size_t)growA * D + (kt - 2) * 32 + q * 8);
                    e0 = ep[0]; e1 = ep[1];
                }
                af[0] = (short)f2bf(bf2f((unsigned short)lv[0]) * e0.x);
                af[1] = (short)f2bf(bf2f((unsigned short)lv[1]) * e0.y);
                af[2] = (short)f2bf(bf2f((unsigned short)lv[2]) * e0.z);
                af[3] = (short)f2bf(bf2f((unsigned short)lv[3]) * e0.w);
                af[4] = (short)f2bf(bf2f((unsigned short)lv[4]) * e1.x);
                af[5] = (short)f2bf(bf2f((unsigned short)lv[5]) * e1.y);
                af[6] = (short)f2bf(bf2f((unsigned short)lv[6]) * e1.z);
                af[7] = (short)f2bf(bf2f((unsigned short)lv[7]) * e1.w);
            }
#pragma unroll
            for (int jt = 0; jt < 4; ++jt) {
                const short8 bf = *(const short8*)(Wfrag + (size_t)(jt * 4 + kt) * 512 + (size_t)l * 8);
                accv[jt] = __builtin_amdgcn_mfma_f32_16x16x32_bf16(af, bf, accv[jt], 0, 0, 0);
            }
        }

#pragma unroll
        for (int jt = 0; jt < 4; ++jt) {
#pragma unroll
            for (int r = 0; r < 4; ++r) {
                int grow = rowbase + q * 4 + r;
                if (grow < n) {
                    float v = accv[jt][r];
                    v = v > 0.f ? v : 0.2f * v;
                    out[(size_t)grow * D + jt * 16 + mcol] = v;
                }
            }
        }
    }
}

// ---------------------------------------------------------------------------
// Fallback path (workspace too small): R1 atomic scatter + fp32 epilogue.
// ---------------------------------------------------------------------------
__global__ void scatter_kernel(
    const float* __restrict__ LI_vals, const int* __restrict__ LI_rows, const int* __restrict__ LI_cols,
    const float* __restrict__ L_vals,  const int* __restrict__ L_rows,  const int* __restrict__ L_cols,
    const float* __restrict__ ebs,
    float* __restrict__ accLI, float* __restrict__ accL, int E)
{
    long long t = (long long)blockIdx.x * blockDim.x + threadIdx.x;
    long long e2 = t >> 4;
    if (e2 >= 2LL * E) return;
    int c = ((int)t & 15) << 2;
    const float* vals; const int* rows; const int* cols; float* acc; int e;
    if (e2 < E) { vals = LI_vals; rows = LI_rows; cols = LI_cols; acc = accLI; e = (int)e2; }
    else        { vals = L_vals;  rows = L_rows;  cols = L_cols;  acc = accL;  e = (int)(e2 - E); }
    float v = vals[e]; int r = rows[e]; int cl = cols[e];
    const float4 x = *(const float4*)(ebs + (size_t)cl * D + c);
    float* o = acc + (size_t)r * D + c;
    unsafeAtomicAdd(o + 0, v * x.x);
    unsafeAtomicAdd(o + 1, v * x.y);
    unsafeAtomicAdd(o + 2, v * x.z);
    unsafeAtomicAdd(o + 3, v * x.w);
}

__global__ __launch_bounds__(256) void epilogue_kernel(
    const float* __restrict__ acc, const float* __restrict__ entity,
    const float* __restrict__ W_side, const float* __restrict__ W_dot,
    float* __restrict__ out, int n)
{
    int lane = threadIdx.x & 63;
    int wave = (blockIdx.x << 2) | (threadIdx.x >> 6);
    int row  = (wave << 6) + lane;
    bool valid = row < n;
    const float* accLI = acc;
    const float* accL  = acc + (size_t)n * D;
    float a[D], b[D];
    if (valid) {
        const float4* ap = (const float4*)(accLI  + (size_t)row * D);
        const float4* lp = (const float4*)(accL   + (size_t)row * D);
        const float4* ep = (const float4*)(entity + (size_t)row * D);
#pragma unroll
        for (int qq = 0; qq < 16; ++qq) {
            float4 av = ap[qq]; float4 lv = lp[qq]; float4 ev = ep[qq];
            a[4*qq+0] = av.x; a[4*qq+1] = av.y; a[4*qq+2] = av.z; a[4*qq+3] = av.w;
            b[4*qq+0] = lv.x * ev.x; b[4*qq+1] = lv.y * ev.y;
            b[4*qq+2] = lv.z * ev.z; b[4*qq+3] = lv.w * ev.w;
        }
    } else {
#pragma unroll
        for (int qq = 0; qq < D; ++qq) { a[qq] = 0.f; b[qq] = 0.f; }
    }
    float4* op = (float4*)(out + (size_t)row * D);
#pragma unroll 1
    for (int jc = 0; jc < 16; ++jc) {
        float a0 = 0.f, a1 = 0.f, a2 = 0.f, a3 = 0.f;
#pragma unroll
        for (int k = 0; k < D; ++k) {
            float4 w1 = *(const float4*)(W_side + (k << 6) + (jc << 2));
            float4 w2 = *(const float4*)(W_dot  + (k << 6) + (jc << 2));
            a0 += a[k] * w1.x + b[k] * w2.x;
            a1 += a[k] * w1.y + b[k] * w2.y;
            a2 += a[k] * w1.z + b[k] * w2.z;
            a3 += a[k] * w1.w + b[k] * w2.w;
        }
        float4 r;
        r.x = a0 > 0.f ? a0 : 0.2f * a0;
        r.y = a1 > 0.f ? a1 : 0.2f * a1;
        r.z = a2 > 0.f ? a2 : 0.2f * a2;
        r.w = a3 > 0.f ? a3 : 0.2f * a3;
        if (valid) op[jc] = r;
    }
}

extern "C" void kernel_launch(void* const* d_in, const int* in_sizes, int n_in,
                              void* d_out, int out_size, void* d_ws, size_t ws_size,
                              hipStream_t stream) {
    const float* ebs     = (const float*)d_in[0];
    const float* entity  = (const float*)d_in[1];
    const float* W_side  = (const float*)d_in[2];
    const float* W_dot   = (const float*)d_in[3];
    const float* LI_vals = (const float*)d_in[4];
    const float* L_vals  = (const float*)d_in[5];
    const int*   LI_rows = (const int*)d_in[6];
    const int*   LI_cols = (const int*)d_in[7];
    const int*   L_rows  = (const int*)d_in[8];
    const int*   L_cols  = (const int*)d_in[9];
    float* out = (float*)d_out;

    int E = in_sizes[4];
    int n = in_sizes[0] / D;
    int nbins = (n + BINROWS - 1) / BINROWS;

    size_t curBytes = (size_t)NSHARD * NBINS_MAX * CURSTRIDE * sizeof(int);   // 0.80 MB
    size_t segBytes = (size_t)NSHARD * NBINS_MAX * SUBCAP * sizeof(uint2);    // 25.7 MB
    size_t ebsBytes = (size_t)n * D * sizeof(unsigned short);                 // 12.8 MB
    size_t wfBytes  = (size_t)16 * 512 * sizeof(unsigned short);              // 16 KB
    size_t need = curBytes + segBytes + ebsBytes + wfBytes;

    if (ws_size >= need && nbins <= NBINS_MAX && n <= 131072) {
        int*            cursorP = (int*)d_ws;
        uint2*          seg     = (uint2*)((char*)d_ws + curBytes);
        unsigned short* ebs16   = (unsigned short*)((char*)d_ws + curBytes + segBytes);
        unsigned short* Wfrag   = (unsigned short*)((char*)d_ws + curBytes + segBytes + ebsBytes);

        hipMemsetAsync(cursorP, 0, curBytes, stream);

        int total4 = n * D / 4;
        int xblocks = (2 * E + CHUNK - 1) / CHUNK;
        expand_bin_kernel<<<xblocks, 256, 0, stream>>>(
            LI_rows, LI_cols, LI_vals, L_rows, L_cols, L_vals,
            cursorP, seg, E, nbins,
            ebs, ebs16, total4, W_side, W_dot, Wfrag);

        fused_kernel<<<nbins, FTH, 0, stream>>>(
            seg, cursorP, ebs16, entity, Wfrag, out, n);
    } else {
        size_t accBytes = (size_t)2 * n * D * sizeof(float);
        float* acc   = (float*)d_ws;
        float* accLI = acc;
        float* accL  = accLI + (size_t)n * D;
        hipMemsetAsync(d_ws, 0, accBytes, stream);
        long long totalThreads = 2LL * E * 16;
        int sblocks = (int)((totalThreads + 255) / 256);
        scatter_kernel<<<sblocks, 256, 0, stream>>>(
            LI_vals, LI_rows, LI_cols, L_vals, L_rows, L_cols, ebs, accLI, accL, E);
        int nTiles = (n + 63) / 64;
        epilogue_kernel<<<(nTiles + 3) / 4, 256, 0, stream>>>(
            acc, entity, W_side, W_dot, out, n);
    }
}